// Round 2
// baseline (302.181 us; speedup 1.0000x reference)
//
#include <hip/hip_runtime.h>
#include <hip/hip_bf16.h>
#include <hip/hip_fp16.h>
#include <math.h>

#define NNODES 50000
#define NEDGES 800000
#define FIN 128
#define FH 256
#define NG 64
#define NC 64
#define SCAN_NB ((NNODES + 255) / 256)       // 196
#define NP 50176              // K padded to 196*256
#define QSK 196               // split-K blocks for qsum (NP/256)
#define DEG_BLOCKS ((NEDGES + 255) / 256)    // 3125
#define SPLITX_ITEMS (NNODES * FIN / 4)      // 1.6M
#define SPLITX_BLOCKS ((SPLITX_ITEMS + 255) / 256)   // 6250
#define GEMM_MB ((NNODES + 127) / 128)       // 391
#define GEMM_BLKS (GEMM_MB * 2)              // 782
#define QTR (NP / 4)                         // 12544 src slots per wt-build block

typedef unsigned short bhalf;
typedef __attribute__((ext_vector_type(8))) short bf16x8;
typedef __attribute__((ext_vector_type(4))) float f32x4;
typedef __attribute__((ext_vector_type(4))) unsigned short u16x4;

__device__ inline bhalf f2bf_rn(float f) {
    unsigned int u = __float_as_uint(f);
    u += 0x7FFFu + ((u >> 16) & 1u);      // round-to-nearest-even
    return (bhalf)(u >> 16);
}
__device__ inline float bf2f(bhalf h) { return __uint_as_float(((unsigned int)h) << 16); }
__device__ inline float2 bfpair(unsigned int u) {   // [lo16, hi16] -> two floats
    return make_float2(__uint_as_float(u << 16), __uint_as_float(u & 0xFFFF0000u));
}

// ---------------- degree count + x->bf16 (2 block ranges) ----------------
// No rank array: CSR placement uses an atomic cursor later. No wt zeroing:
// wt is never materialized in f32 (built per-graph in LDS instead).

__global__ void degree_splitx_kernel(const int* __restrict__ dst, int* __restrict__ degi,
                                     const float* __restrict__ x, bhalf* __restrict__ xb) {
    int b = blockIdx.x;
    if (b < DEG_BLOCKS) {
        int e = b * 256 + threadIdx.x;
        if (e < NEDGES) atomicAdd(&degi[dst[e]], 1);
    } else {
        int i = (b - DEG_BLOCKS) * 256 + threadIdx.x;
        if (i < SPLITX_ITEMS) {
            float4 v = *reinterpret_cast<const float4*>(&x[i * 4]);
            u16x4 o = {f2bf_rn(v.x), f2bf_rn(v.y), f2bf_rn(v.z), f2bf_rn(v.w)};
            *reinterpret_cast<u16x4*>(&xb[i * 4]) = o;
        }
    }
}

// ---------------- block-scan over degi (per-block sums to partial) + fused dinv ----------------

__global__ __launch_bounds__(256)
void scan_block_kernel(const int* __restrict__ degi, int* __restrict__ local_ex,
                       int* __restrict__ partial, float* __restrict__ dinv, int Nn) {
    __shared__ int s[256];
    int i = blockIdx.x * 256 + threadIdx.x;
    int v = (i < Nn) ? degi[i] : 0;
    s[threadIdx.x] = v;
    __syncthreads();
#pragma unroll
    for (int off = 1; off < 256; off <<= 1) {
        int t = (threadIdx.x >= off) ? s[threadIdx.x - off] : 0;
        __syncthreads();
        s[threadIdx.x] += t;
        __syncthreads();
    }
    if (i < Nn) {
        local_ex[i] = s[threadIdx.x] - v;
        dinv[i] = rsqrtf((float)v + 1.0f);
    }
    if (threadIdx.x == 255) partial[blockIdx.x] = s[255];   // raw block sum
}

// ---------------- add offsets (computes own block prefix) + cursor copy + split_w ----------------

__global__ __launch_bounds__(256)
void add_offsets_kernel(int* __restrict__ row_start, int* __restrict__ cursor,
                        const int* __restrict__ local_ex, const int* __restrict__ partial,
                        const float* __restrict__ W1, bhalf* __restrict__ w1t, int Nn) {
    __shared__ int s[256];
    int t = threadIdx.x;
    s[t] = (t < blockIdx.x) ? partial[t] : 0;   // SCAN_NB (196) <= 256
    __syncthreads();
#pragma unroll
    for (int off = 128; off > 0; off >>= 1) {
        if (t < off) s[t] += s[t + off];
        __syncthreads();
    }
    int prefix = s[0];
    int i = blockIdx.x * 256 + t;
    if (i < Nn) {
        int rs = local_ex[i] + prefix;
        row_start[i] = rs;
        cursor[i] = rs;
    }
    if (i < FIN * 256) {                        // fused split_w: W1[K][256] -> w1t[256][K]
        int k = i >> 8, n = i & 255;
        w1t[n * FIN + k] = f2bf_rn(W1[i]);
    }
}

// ---------------- edge placement: 8B entries {src, f32 norm}, cursor-based pos ----------------
// No wt atomics here anymore: the 800K random f32 atomics (≈51MB of EA write
// transactions, the bulk of the old 58MB WRITE_SIZE) are eliminated.

__global__ void edge_place_kernel(const int* __restrict__ src, const int* __restrict__ dst,
                                  int* __restrict__ cursor, const float* __restrict__ dinv,
                                  uint2* __restrict__ edata, int E) {
    int e = blockIdx.x * blockDim.x + threadIdx.x;
    if (e >= E) return;
    int s = src[e], d = dst[e];
    int pos = atomicAdd(&cursor[d], 1);
    float nm = dinv[s] * dinv[d];
    edata[pos] = make_uint2((unsigned int)s, __float_as_uint(nm));
}

// ---------------- CSR gather, 128 bf16 feats: z[n] = bf16(sum + x[n]*sn), unroll-4 ----------------

__global__ __launch_bounds__(256)
void gather128_kernel(const bhalf* __restrict__ xb, const uint2* __restrict__ edata,
                      const int* __restrict__ row_start, const int* __restrict__ degi,
                      const float* __restrict__ dinv, bhalf* __restrict__ z, int Nn) {
    int node = blockIdx.x * 4 + (threadIdx.x >> 6);
    if (node >= Nn) return;
    int lane = threadIdx.x & 63;
    int st = row_start[node];
    int cnt = degi[node];
    float ax = 0.0f, ay = 0.0f;
    int j = 0;
    for (; j + 3 < cnt; j += 4) {
        uint2 e0 = edata[st + j],     e1 = edata[st + j + 1];
        uint2 e2 = edata[st + j + 2], e3 = edata[st + j + 3];
        float2 v0 = bfpair(*reinterpret_cast<const unsigned int*>(&xb[(size_t)e0.x * FIN + lane * 2]));
        float2 v1 = bfpair(*reinterpret_cast<const unsigned int*>(&xb[(size_t)e1.x * FIN + lane * 2]));
        float2 v2 = bfpair(*reinterpret_cast<const unsigned int*>(&xb[(size_t)e2.x * FIN + lane * 2]));
        float2 v3 = bfpair(*reinterpret_cast<const unsigned int*>(&xb[(size_t)e3.x * FIN + lane * 2]));
        float n0 = __uint_as_float(e0.y), n1 = __uint_as_float(e1.y);
        float n2 = __uint_as_float(e2.y), n3 = __uint_as_float(e3.y);
        ax += v0.x * n0 + v1.x * n1 + v2.x * n2 + v3.x * n3;
        ay += v0.y * n0 + v1.y * n1 + v2.y * n2 + v3.y * n3;
    }
    for (; j < cnt; j++) {
        uint2 e0 = edata[st + j];
        float2 v0 = bfpair(*reinterpret_cast<const unsigned int*>(&xb[(size_t)e0.x * FIN + lane * 2]));
        float n0 = __uint_as_float(e0.y);
        ax += v0.x * n0; ay += v0.y * n0;
    }
    float sn = dinv[node];
    sn *= sn;
    float2 xv = bfpair(*reinterpret_cast<const unsigned int*>(&xb[(size_t)node * FIN + lane * 2]));
    ushort2 o = {f2bf_rn(ax + xv.x * sn), f2bf_rn(ay + xv.y * sn)};
    *reinterpret_cast<ushort2*>(&z[(size_t)node * FIN + lane * 2]) = o;
}

// ---------------- wt build from CSR: one block per (graph, src-quarter) ----------------
// batch is sorted, edata is sorted by dst => graph g's edges are the contiguous
// CSR span [row_start[na], row_start[nb]). Sequential reads + LDS f32 atomics
// replace 800K random global atomics. Writes wthi/wtlo bf16 hi/lo coalesced
// (f32 wt array + separate cvt kernel deleted).

__global__ __launch_bounds__(256)
void wt_build_kernel(const uint2* __restrict__ edata, const int* __restrict__ row_start,
                     const int* __restrict__ batch, const float* __restrict__ dinv,
                     bhalf* __restrict__ wthi, bhalf* __restrict__ wtlo) {
    __shared__ float acc[QTR];
    int g = blockIdx.x >> 2;
    int q = blockIdx.x & 3;
    int base = q * QTR;
    for (int i = threadIdx.x; i < QTR; i += 256) acc[i] = 0.0f;
    // node range [na, nb) of graph g (batch sorted)
    int lo = 0, hi = NNODES;
    while (lo < hi) { int m = (lo + hi) >> 1; if (batch[m] < g) lo = m + 1; else hi = m; }
    int na = lo;
    hi = NNODES;               // nb >= na since sorted
    while (lo < hi) { int m = (lo + hi) >> 1; if (batch[m] < g + 1) lo = m + 1; else hi = m; }
    int nb = lo;
    int pa = (na < NNODES) ? row_start[na] : NEDGES;
    int pb = (nb < NNODES) ? row_start[nb] : NEDGES;
    __syncthreads();
    for (int p = pa + threadIdx.x; p < pb; p += 256) {
        uint2 e = edata[p];
        int s = (int)e.x - base;
        if ((unsigned int)s < (unsigned int)QTR)
            atomicAdd(&acc[s], __uint_as_float(e.y));
    }
    __syncthreads();
    size_t rowo = (size_t)g * NP + base;
    for (int i = threadIdx.x; i < QTR; i += 256) {
        int s = base + i;
        float v = acc[i];
        if (s >= na && s < nb) { float dv = dinv[s]; v += dv * dv; }   // self-loop
        bhalf hb = f2bf_rn(v);
        wthi[rowo + i] = hb;
        wtlo[rowo + i] = f2bf_rn(v - bf2f(hb));
    }
}

// ---------------- MFMA bf16 GEMM (transposed out): h1t = bf16(gelu(zb@w1t^T + b1))^T ----------------

__global__ __launch_bounds__(256)
void gemm_kernel(const bhalf* __restrict__ A, const bhalf* __restrict__ Bt,
                 const float* __restrict__ bias, bhalf* __restrict__ h1t, int M, int Kp) {
    __shared__ bhalf As[128 * 72];   // rows x (64+8 pad): 144 B row stride
    __shared__ bhalf Bs[128 * 72];
    const int tid  = threadIdx.x;
    const int lane = tid & 63;
    const int wave = tid >> 6;
    const int quad = lane >> 4;
    const int l15  = lane & 15;
    const int wm = (wave & 1) * 64;
    const int wn = (wave >> 1) * 64;
    const int bm = (blockIdx.x >> 1) * 128;
    const int bn = (blockIdx.x & 1) * 128;

    f32x4 acc[4][4] = {};

    for (int k0 = 0; k0 < Kp; k0 += 64) {
#pragma unroll
        for (int i = 0; i < 4; i++) {
            int chunk = tid + i * 256;           // 1024 chunks of 8 bf16
            int r = chunk >> 3, c16 = chunk & 7;
            int gm = bm + r;
            float4 va = make_float4(0.f, 0.f, 0.f, 0.f);
            if (gm < M) va = *reinterpret_cast<const float4*>(&A[(size_t)gm * Kp + k0 + c16 * 8]);
            *reinterpret_cast<float4*>(&As[r * 72 + c16 * 8]) = va;
            float4 vb = *reinterpret_cast<const float4*>(&Bt[(size_t)(bn + r) * Kp + k0 + c16 * 8]);
            *reinterpret_cast<float4*>(&Bs[r * 72 + c16 * 8]) = vb;
        }
        __syncthreads();
#pragma unroll
        for (int kk = 0; kk < 64; kk += 32) {
            bf16x8 af[4], bfr[4];
#pragma unroll
            for (int mi = 0; mi < 4; mi++)
                af[mi] = *reinterpret_cast<const bf16x8*>(&As[(wm + mi * 16 + l15) * 72 + kk + quad * 8]);
#pragma unroll
            for (int ni = 0; ni < 4; ni++)
                bfr[ni] = *reinterpret_cast<const bf16x8*>(&Bs[(wn + ni * 16 + l15) * 72 + kk + quad * 8]);
#pragma unroll
            for (int mi = 0; mi < 4; mi++)
#pragma unroll
                for (int ni = 0; ni < 4; ni++)
                    acc[mi][ni] = __builtin_amdgcn_mfma_f32_16x16x32_bf16(af[mi], bfr[ni], acc[mi][ni], 0, 0, 0);
        }
        __syncthreads();
    }

    // epilogue: C/D col = lane&15, row = quad*4 + r. Write transposed: h1t[col][row0..row0+3].
#pragma unroll
    for (int mi = 0; mi < 4; mi++) {
        int row0 = bm + wm + mi * 16 + quad * 4;
#pragma unroll
        for (int ni = 0; ni < 4; ni++) {
            int col = bn + wn + ni * 16 + l15;
            float bv = bias[col];
            u16x4 o;
#pragma unroll
            for (int r = 0; r < 4; r++) {
                float v = acc[mi][ni][r] + bv;
                v = 0.5f * v * (1.0f + erff(v * 0.70710678118654752f));
                o[r] = f2bf_rn(v);
            }
            *reinterpret_cast<u16x4*>(&h1t[(size_t)col * NP + row0]) = o;
        }
    }
}

// ---------------- qsum MFMA: qpart[b][g][k] = h1t @ {wthi,wtlo}^T over K chunk ----------------
// [g][k] layout: f32x4 stores (r=0..3 consecutive k), coalesced p2fc reads.

__global__ __launch_bounds__(256)
void qsum_mfma_kernel(const bhalf* __restrict__ h1t, const bhalf* __restrict__ wthi,
                      const bhalf* __restrict__ wtlo, float* __restrict__ qpart) {
    const int tid  = threadIdx.x;
    const int lane = tid & 63;
    const int wave = tid >> 6;
    const int quad = lane >> 4;
    const int l15  = lane & 15;
    const int m0 = wave * 64;
    const size_t kbase = (size_t)blockIdx.x * 256 + quad * 8;
    f32x4 acc[4][4] = {};
#pragma unroll
    for (int ks = 0; ks < 8; ks++) {
        size_t k0 = kbase + ks * 32;
        bf16x8 af[4], bh[4], bl[4];
#pragma unroll
        for (int mi = 0; mi < 4; mi++)
            af[mi] = *reinterpret_cast<const bf16x8*>(&h1t[(size_t)(m0 + mi * 16 + l15) * NP + k0]);
#pragma unroll
        for (int ni = 0; ni < 4; ni++) {
            bh[ni] = *reinterpret_cast<const bf16x8*>(&wthi[(size_t)(ni * 16 + l15) * NP + k0]);
            bl[ni] = *reinterpret_cast<const bf16x8*>(&wtlo[(size_t)(ni * 16 + l15) * NP + k0]);
        }
#pragma unroll
        for (int mi = 0; mi < 4; mi++)
#pragma unroll
            for (int ni = 0; ni < 4; ni++) {
                acc[mi][ni] = __builtin_amdgcn_mfma_f32_16x16x32_bf16(af[mi], bh[ni], acc[mi][ni], 0, 0, 0);
                acc[mi][ni] = __builtin_amdgcn_mfma_f32_16x16x32_bf16(af[mi], bl[ni], acc[mi][ni], 0, 0, 0);
            }
    }
    float* qp = &qpart[(size_t)blockIdx.x * NG * FH];
#pragma unroll
    for (int mi = 0; mi < 4; mi++) {
        int row0 = m0 + mi * 16 + quad * 4;          // k-dim 0..255 (4 consecutive)
#pragma unroll
        for (int ni = 0; ni < 4; ni++) {
            int col = ni * 16 + l15;                 // g-dim 0..63
            f32x4 o = {acc[mi][ni][0], acc[mi][ni][1], acc[mi][ni][2], acc[mi][ni][3]};
            *reinterpret_cast<f32x4*>(&qp[(size_t)col * FH + row0]) = o;
        }
    }
}

// ---------------- fused head: q-reduce + pooled = (q@W2)/cnt + b2 ; out = pooled@Wfc + bfc ----------------

__global__ __launch_bounds__(256)
void p2fc_kernel(const float* __restrict__ qpart, const float* __restrict__ W2,
                 const float* __restrict__ b2, const int* __restrict__ batch,
                 const float* __restrict__ Wfc, const float* __restrict__ bfc,
                 float* __restrict__ out) {
    __shared__ float qg[FH];
    __shared__ float ps[FH];
    int g = blockIdx.x;
    int t = threadIdx.x;
    float s = 0.0f;
    for (int b = 0; b < QSK; b++)                    // coalesced: consecutive t -> consecutive k
        s += qpart[(size_t)b * NG * FH + (size_t)g * FH + t];
    qg[t] = s;
    int lo = 0, hi = NNODES;
    while (lo < hi) { int m = (lo + hi) >> 1; if (batch[m] < g) lo = m + 1; else hi = m; }
    int a = lo;
    lo = 0; hi = NNODES;
    while (lo < hi) { int m = (lo + hi) >> 1; if (batch[m] < g + 1) lo = m + 1; else hi = m; }
    float inv = 1.0f / fmaxf((float)(lo - a), 1.0f);
    __syncthreads();
    float acc = 0.0f;
    for (int k = 0; k < FH; k++)
        acc += qg[k] * W2[k * FH + t];
    ps[t] = acc * inv + b2[t];
    __syncthreads();
    if (t < NC) {
        float a2 = 0.0f;
        for (int cc = 0; cc < FH; cc++)
            a2 += ps[cc] * Wfc[cc * NC + t];
        out[g * NC + t] = a2 + bfc[t];
    }
}

// ---------------- launch ----------------

extern "C" void kernel_launch(void* const* d_in, const int* in_sizes, int n_in,
                              void* d_out, int out_size, void* d_ws, size_t ws_size,
                              hipStream_t stream) {
    const float* x    = (const float*)d_in[0];
    const int*   ei   = (const int*)d_in[1];
    const int*   batch= (const int*)d_in[2];
    const float* W1   = (const float*)d_in[3];
    const float* b1   = (const float*)d_in[4];
    const float* W2   = (const float*)d_in[5];
    const float* b2   = (const float*)d_in[6];
    const float* Wfc  = (const float*)d_in[7];
    const float* bfc  = (const float*)d_in[8];
    float* out = (float*)d_out;

    const int* src = ei;
    const int* dst = ei + NEDGES;

    // workspace (~85 MB):
    bhalf* xb        = (bhalf*)d_ws;                       // [N,128] bf16 (12.8 MB)
    bhalf* zb        = xb + (size_t)NNODES * FIN;          // [N,128] bf16 (12.8 MB)
    bhalf* h1t       = zb + (size_t)NNODES * FIN;          // [256,NP] bf16 (25.7 MB)
    uint2* edata     = (uint2*)(h1t + (size_t)FH * NP);    // [E] {src, f32 norm} (6.4 MB)
    int*   row_start = (int*)(edata + NEDGES);             // [N]
    int*   cursor    = row_start + NNODES;                 // [N]
    int*   local_ex  = cursor + NNODES;                    // [N]
    int*   partial   = local_ex + NNODES;                  // [256]
    float* dinv      = (float*)(partial + 256);            // [N]
    bhalf* w1t       = (bhalf*)(dinv + NNODES);            // [256,128] bf16
    bhalf* wthi      = w1t + 256 * FIN;                    // [64,NP] bf16 (6.4 MB)
    bhalf* wtlo      = wthi + (size_t)NG * NP;             // [64,NP] bf16 (6.4 MB)
    float* qpart     = (float*)(wtlo + (size_t)NG * NP);   // [QSK,64,256] f32, [g][k] (12.85 MB)
    int*   degi      = (int*)(qpart + (size_t)QSK * NG * FH);  // [N] (memset)

    (void)hipMemsetAsync(degi, 0, (size_t)NNODES * 4, stream);

    // ---- CSR build + norms ----
    degree_splitx_kernel<<<DEG_BLOCKS + SPLITX_BLOCKS, 256, 0, stream>>>(dst, degi, x, xb);
    scan_block_kernel<<<SCAN_NB, 256, 0, stream>>>(degi, local_ex, partial, dinv, NNODES);
    add_offsets_kernel<<<SCAN_NB, 256, 0, stream>>>(row_start, cursor, local_ex, partial,
                                                    W1, w1t, NNODES);
    edge_place_kernel<<<(NEDGES + 255) / 256, 256, 0, stream>>>(src, dst, cursor, dinv,
                                                                edata, NEDGES);

    // conv1 (aggregate-first): z = bf16(Ahat*x) ; h1t = bf16(gelu(z@W1 + b1))^T
    gather128_kernel<<<(NNODES + 3) / 4, 256, 0, stream>>>(xb, edata, row_start, degi,
                                                           dinv, zb, NNODES);
    // pooling-weight matrix straight to bf16 hi/lo from CSR (no global atomics)
    wt_build_kernel<<<NG * 4, 256, 0, stream>>>(edata, row_start, batch, dinv, wthi, wtlo);
    gemm_kernel<<<GEMM_BLKS, 256, 0, stream>>>(zb, w1t, b1, h1t, NNODES, FIN);

    // conv2 + pool collapsed via MFMA: qT = h1t @ wt^T ; out = ((q@W2)/cnt + b2)@Wfc + bfc
    qsum_mfma_kernel<<<QSK, 256, 0, stream>>>(h1t, wthi, wtlo, qpart);
    p2fc_kernel<<<NG, FH, 0, stream>>>(qpart, W2, b2, batch, Wfc, bfc, out);
}

// Round 3
// 294.478 us; speedup vs baseline: 1.0262x; 1.0262x over previous
//
#include <hip/hip_runtime.h>
#include <hip/hip_bf16.h>
#include <hip/hip_fp16.h>
#include <math.h>

#define NNODES 50000
#define NEDGES 800000
#define FIN 128
#define FH 256
#define NG 64
#define NC 64
#define SCAN_NB ((NNODES + 255) / 256)       // 196
#define NP 50176              // K padded to 196*256
#define QSK 196               // split-K blocks for qsum (NP/256)
#define DEG_BLOCKS ((NEDGES + 255) / 256)    // 3125
#define SPLITX_ITEMS (NNODES * FIN / 4)      // 1.6M
#define SPLITX_BLOCKS ((SPLITX_ITEMS + 255) / 256)   // 6250
#define GEMM_MB ((NNODES + 127) / 128)       // 391
#define GEMM_BLKS (GEMM_MB * 2)              // 782
#define QTR (NP / 4)                         // 12544 src slots per wt-build block

#define NBUCK 196             // dst>>8 buckets (256 nodes each)
#define BCAP 5120             // per-bucket capacity (mean 4082, sigma ~64 -> +16 sigma)
#define BIN_CHUNK 4096        // edges per bin block
#define BIN_BLOCKS ((NEDGES + BIN_CHUNK - 1) / BIN_CHUNK)   // 196

typedef unsigned short bhalf;
typedef __attribute__((ext_vector_type(8))) short bf16x8;
typedef __attribute__((ext_vector_type(4))) float f32x4;
typedef __attribute__((ext_vector_type(4))) unsigned short u16x4;

__device__ inline bhalf f2bf_rn(float f) {
    unsigned int u = __float_as_uint(f);
    u += 0x7FFFu + ((u >> 16) & 1u);      // round-to-nearest-even
    return (bhalf)(u >> 16);
}
__device__ inline float bf2f(bhalf h) { return __uint_as_float(((unsigned int)h) << 16); }
__device__ inline float2 bfpair(unsigned int u) {   // [lo16, hi16] -> two floats
    return make_float2(__uint_as_float(u << 16), __uint_as_float(u & 0xFFFF0000u));
}

// ---------------- degree count + x->bf16 (2 block ranges) ----------------

__global__ void degree_splitx_kernel(const int* __restrict__ dst, int* __restrict__ degi,
                                     const float* __restrict__ x, bhalf* __restrict__ xb) {
    int b = blockIdx.x;
    if (b < DEG_BLOCKS) {
        int e = b * 256 + threadIdx.x;
        if (e < NEDGES) atomicAdd(&degi[dst[e]], 1);
    } else {
        int i = (b - DEG_BLOCKS) * 256 + threadIdx.x;
        if (i < SPLITX_ITEMS) {
            float4 v = *reinterpret_cast<const float4*>(&x[i * 4]);
            u16x4 o = {f2bf_rn(v.x), f2bf_rn(v.y), f2bf_rn(v.z), f2bf_rn(v.w)};
            *reinterpret_cast<u16x4*>(&xb[i * 4]) = o;
        }
    }
}

// ---------------- block-scan over degi (per-block sums to partial) + fused dinv ----------------

__global__ __launch_bounds__(256)
void scan_block_kernel(const int* __restrict__ degi, int* __restrict__ local_ex,
                       int* __restrict__ partial, float* __restrict__ dinv, int Nn) {
    __shared__ int s[256];
    int i = blockIdx.x * 256 + threadIdx.x;
    int v = (i < Nn) ? degi[i] : 0;
    s[threadIdx.x] = v;
    __syncthreads();
#pragma unroll
    for (int off = 1; off < 256; off <<= 1) {
        int t = (threadIdx.x >= off) ? s[threadIdx.x - off] : 0;
        __syncthreads();
        s[threadIdx.x] += t;
        __syncthreads();
    }
    if (i < Nn) {
        local_ex[i] = s[threadIdx.x] - v;
        dinv[i] = rsqrtf((float)v + 1.0f);
    }
    if (threadIdx.x == 255) partial[blockIdx.x] = s[255];   // raw block sum
}

// ---------------- add offsets (computes own block prefix) + bcur init + split_w ----------------

__global__ __launch_bounds__(256)
void add_offsets_kernel(int* __restrict__ row_start, const int* __restrict__ local_ex,
                        const int* __restrict__ partial, int* __restrict__ bcur,
                        const float* __restrict__ W1, bhalf* __restrict__ w1t, int Nn) {
    __shared__ int s[256];
    int t = threadIdx.x;
    s[t] = (t < blockIdx.x) ? partial[t] : 0;   // SCAN_NB (196) <= 256
    __syncthreads();
#pragma unroll
    for (int off = 128; off > 0; off >>= 1) {
        if (t < off) s[t] += s[t + off];
        __syncthreads();
    }
    int prefix = s[0];
    int i = blockIdx.x * 256 + t;
    if (i < Nn) row_start[i] = local_ex[i] + prefix;
    if (blockIdx.x == 0 && t < NBUCK) bcur[t] = t * BCAP;   // bucket cursors
    if (i < FIN * 256) {                        // fused split_w: W1[K][256] -> w1t[256][K]
        int k = i >> 8, n = i & 255;
        w1t[n * FIN + k] = f2bf_rn(W1[i]);
    }
}

// ---------------- pass 1: bucket binning with LDS staging, coalesced flushes ----------------
// Kills the x8 XCD partial-line writeback amplification of the old random
// scatter: entries are staged bucket-major in LDS, space reserved with ONE
// global atomic per (block,bucket), then flushed so consecutive staged
// entries hit consecutive global positions.

__global__ __launch_bounds__(256)
void bin_kernel(const int* __restrict__ src, const int* __restrict__ dst,
                const float* __restrict__ dinv, int* __restrict__ bcur,
                uint2* __restrict__ binned) {
    __shared__ int hist[NBUCK];
    __shared__ int base[NBUCK];
    __shared__ int gb[NBUCK];
    __shared__ int lcur[NBUCK];
    __shared__ int scan_tmp[256];
    __shared__ uint2 stage[BIN_CHUNK];
    __shared__ unsigned char bid[BIN_CHUNK];
    int t = threadIdx.x;
    int e0 = blockIdx.x * BIN_CHUNK;
    for (int i = t; i < NBUCK; i += 256) hist[i] = 0;
    __syncthreads();
#pragma unroll
    for (int k = 0; k < BIN_CHUNK / 256; k++) {
        int e = e0 + k * 256 + t;
        if (e < NEDGES) atomicAdd(&hist[dst[e] >> 8], 1);
    }
    __syncthreads();
    // inclusive Hillis-Steele scan over 256 (NBUCK padded with zeros)
    int v = (t < NBUCK) ? hist[t] : 0;
    scan_tmp[t] = v;
    __syncthreads();
#pragma unroll
    for (int off = 1; off < 256; off <<= 1) {
        int x = (t >= off) ? scan_tmp[t - off] : 0;
        __syncthreads();
        scan_tmp[t] += x;
        __syncthreads();
    }
    if (t < NBUCK) {
        int ex = scan_tmp[t] - v;                // exclusive
        base[t] = ex;
        lcur[t] = ex;
        gb[t] = (v > 0) ? atomicAdd(&bcur[t], v) : 0;
    }
    __syncthreads();
#pragma unroll
    for (int k = 0; k < BIN_CHUNK / 256; k++) {
        int e = e0 + k * 256 + t;
        if (e < NEDGES) {
            int s = src[e], d = dst[e];
            int b = d >> 8;
            float nm = dinv[s] * dinv[d];
            int lp = atomicAdd(&lcur[b], 1);
            stage[lp] = make_uint2((unsigned int)s | ((unsigned int)(d & 255) << 17),
                                   __float_as_uint(nm));
            bid[lp] = (unsigned char)b;          // b < 196 fits u8
        }
    }
    __syncthreads();
    int total = base[NBUCK - 1] + hist[NBUCK - 1];
    for (int i = t; i < total; i += 256) {
        int b = bid[i];
        binned[(size_t)gb[b] + (i - base[b])] = stage[i];
    }
}

// ---------------- pass 2: per-bucket CSR placement ----------------
// One block owns one bucket's entire 256-node CSR span (~33KB): the random
// writes stay inside a single XCD's L2 and write back as FULL lines.

__global__ __launch_bounds__(256)
void place_kernel(const uint2* __restrict__ binned, const int* __restrict__ bcur,
                  const int* __restrict__ row_start, uint2* __restrict__ edata) {
    __shared__ int lcur[256];
    int b = blockIdx.x;
    int t = threadIdx.x;
    lcur[t] = 0;
    __syncthreads();
    int cnt = bcur[b] - b * BCAP;
    int nb0 = b << 8;
    const uint2* bp = &binned[(size_t)b * BCAP];
    for (int i = t; i < cnt; i += 256) {
        uint2 e = bp[i];
        int dl = (e.x >> 17) & 255;
        int pos = row_start[nb0 + dl] + atomicAdd(&lcur[dl], 1);
        edata[pos] = make_uint2(e.x & 0x1FFFFu, e.y);
    }
}

// ---------------- CSR gather, 128 bf16 feats: z[n] = bf16(sum + x[n]*sn), unroll-4 ----------------

__global__ __launch_bounds__(256)
void gather128_kernel(const bhalf* __restrict__ xb, const uint2* __restrict__ edata,
                      const int* __restrict__ row_start, const int* __restrict__ degi,
                      const float* __restrict__ dinv, bhalf* __restrict__ z, int Nn) {
    int node = blockIdx.x * 4 + (threadIdx.x >> 6);
    if (node >= Nn) return;
    int lane = threadIdx.x & 63;
    int st = row_start[node];
    int cnt = degi[node];
    float ax = 0.0f, ay = 0.0f;
    int j = 0;
    for (; j + 3 < cnt; j += 4) {
        uint2 e0 = edata[st + j],     e1 = edata[st + j + 1];
        uint2 e2 = edata[st + j + 2], e3 = edata[st + j + 3];
        float2 v0 = bfpair(*reinterpret_cast<const unsigned int*>(&xb[(size_t)e0.x * FIN + lane * 2]));
        float2 v1 = bfpair(*reinterpret_cast<const unsigned int*>(&xb[(size_t)e1.x * FIN + lane * 2]));
        float2 v2 = bfpair(*reinterpret_cast<const unsigned int*>(&xb[(size_t)e2.x * FIN + lane * 2]));
        float2 v3 = bfpair(*reinterpret_cast<const unsigned int*>(&xb[(size_t)e3.x * FIN + lane * 2]));
        float n0 = __uint_as_float(e0.y), n1 = __uint_as_float(e1.y);
        float n2 = __uint_as_float(e2.y), n3 = __uint_as_float(e3.y);
        ax += v0.x * n0 + v1.x * n1 + v2.x * n2 + v3.x * n3;
        ay += v0.y * n0 + v1.y * n1 + v2.y * n2 + v3.y * n3;
    }
    for (; j < cnt; j++) {
        uint2 e0 = edata[st + j];
        float2 v0 = bfpair(*reinterpret_cast<const unsigned int*>(&xb[(size_t)e0.x * FIN + lane * 2]));
        float n0 = __uint_as_float(e0.y);
        ax += v0.x * n0; ay += v0.y * n0;
    }
    float sn = dinv[node];
    sn *= sn;
    float2 xv = bfpair(*reinterpret_cast<const unsigned int*>(&xb[(size_t)node * FIN + lane * 2]));
    ushort2 o = {f2bf_rn(ax + xv.x * sn), f2bf_rn(ay + xv.y * sn)};
    *reinterpret_cast<ushort2*>(&z[(size_t)node * FIN + lane * 2]) = o;
}

// ---------------- wt build from CSR: one block per (graph, src-quarter) ----------------

__global__ __launch_bounds__(256)
void wt_build_kernel(const uint2* __restrict__ edata, const int* __restrict__ row_start,
                     const int* __restrict__ batch, const float* __restrict__ dinv,
                     bhalf* __restrict__ wthi, bhalf* __restrict__ wtlo) {
    __shared__ float acc[QTR];
    int g = blockIdx.x >> 2;
    int q = blockIdx.x & 3;
    int base = q * QTR;
    for (int i = threadIdx.x; i < QTR; i += 256) acc[i] = 0.0f;
    // node range [na, nb) of graph g (batch sorted)
    int lo = 0, hi = NNODES;
    while (lo < hi) { int m = (lo + hi) >> 1; if (batch[m] < g) lo = m + 1; else hi = m; }
    int na = lo;
    hi = NNODES;               // nb >= na since sorted
    while (lo < hi) { int m = (lo + hi) >> 1; if (batch[m] < g + 1) lo = m + 1; else hi = m; }
    int nb = lo;
    int pa = (na < NNODES) ? row_start[na] : NEDGES;
    int pb = (nb < NNODES) ? row_start[nb] : NEDGES;
    __syncthreads();
    for (int p = pa + threadIdx.x; p < pb; p += 256) {
        uint2 e = edata[p];
        int s = (int)e.x - base;
        if ((unsigned int)s < (unsigned int)QTR)
            atomicAdd(&acc[s], __uint_as_float(e.y));
    }
    __syncthreads();
    size_t rowo = (size_t)g * NP + base;
    for (int i = threadIdx.x; i < QTR; i += 256) {
        int s = base + i;
        float v = acc[i];
        if (s >= na && s < nb) { float dv = dinv[s]; v += dv * dv; }   // self-loop
        bhalf hb = f2bf_rn(v);
        wthi[rowo + i] = hb;
        wtlo[rowo + i] = f2bf_rn(v - bf2f(hb));
    }
}

// ---------------- MFMA bf16 GEMM (transposed out): h1t = bf16(gelu(zb@w1t^T + b1))^T ----------------

__global__ __launch_bounds__(256)
void gemm_kernel(const bhalf* __restrict__ A, const bhalf* __restrict__ Bt,
                 const float* __restrict__ bias, bhalf* __restrict__ h1t, int M, int Kp) {
    __shared__ bhalf As[128 * 72];   // rows x (64+8 pad): 144 B row stride
    __shared__ bhalf Bs[128 * 72];
    const int tid  = threadIdx.x;
    const int lane = tid & 63;
    const int wave = tid >> 6;
    const int quad = lane >> 4;
    const int l15  = lane & 15;
    const int wm = (wave & 1) * 64;
    const int wn = (wave >> 1) * 64;
    const int bm = (blockIdx.x >> 1) * 128;
    const int bn = (blockIdx.x & 1) * 128;

    f32x4 acc[4][4] = {};

    for (int k0 = 0; k0 < Kp; k0 += 64) {
#pragma unroll
        for (int i = 0; i < 4; i++) {
            int chunk = tid + i * 256;           // 1024 chunks of 8 bf16
            int r = chunk >> 3, c16 = chunk & 7;
            int gm = bm + r;
            float4 va = make_float4(0.f, 0.f, 0.f, 0.f);
            if (gm < M) va = *reinterpret_cast<const float4*>(&A[(size_t)gm * Kp + k0 + c16 * 8]);
            *reinterpret_cast<float4*>(&As[r * 72 + c16 * 8]) = va;
            float4 vb = *reinterpret_cast<const float4*>(&Bt[(size_t)(bn + r) * Kp + k0 + c16 * 8]);
            *reinterpret_cast<float4*>(&Bs[r * 72 + c16 * 8]) = vb;
        }
        __syncthreads();
#pragma unroll
        for (int kk = 0; kk < 64; kk += 32) {
            bf16x8 af[4], bfr[4];
#pragma unroll
            for (int mi = 0; mi < 4; mi++)
                af[mi] = *reinterpret_cast<const bf16x8*>(&As[(wm + mi * 16 + l15) * 72 + kk + quad * 8]);
#pragma unroll
            for (int ni = 0; ni < 4; ni++)
                bfr[ni] = *reinterpret_cast<const bf16x8*>(&Bs[(wn + ni * 16 + l15) * 72 + kk + quad * 8]);
#pragma unroll
            for (int mi = 0; mi < 4; mi++)
#pragma unroll
                for (int ni = 0; ni < 4; ni++)
                    acc[mi][ni] = __builtin_amdgcn_mfma_f32_16x16x32_bf16(af[mi], bfr[ni], acc[mi][ni], 0, 0, 0);
        }
        __syncthreads();
    }

    // epilogue: C/D col = lane&15, row = quad*4 + r. Write transposed: h1t[col][row0..row0+3].
#pragma unroll
    for (int mi = 0; mi < 4; mi++) {
        int row0 = bm + wm + mi * 16 + quad * 4;
#pragma unroll
        for (int ni = 0; ni < 4; ni++) {
            int col = bn + wn + ni * 16 + l15;
            float bv = bias[col];
            u16x4 o;
#pragma unroll
            for (int r = 0; r < 4; r++) {
                float v = acc[mi][ni][r] + bv;
                v = 0.5f * v * (1.0f + erff(v * 0.70710678118654752f));
                o[r] = f2bf_rn(v);
            }
            *reinterpret_cast<u16x4*>(&h1t[(size_t)col * NP + row0]) = o;
        }
    }
}

// ---------------- qsum MFMA: qpart[b][g][k] = h1t @ {wthi,wtlo}^T over K chunk ----------------

__global__ __launch_bounds__(256)
void qsum_mfma_kernel(const bhalf* __restrict__ h1t, const bhalf* __restrict__ wthi,
                      const bhalf* __restrict__ wtlo, float* __restrict__ qpart) {
    const int tid  = threadIdx.x;
    const int lane = tid & 63;
    const int wave = tid >> 6;
    const int quad = lane >> 4;
    const int l15  = lane & 15;
    const int m0 = wave * 64;
    const size_t kbase = (size_t)blockIdx.x * 256 + quad * 8;
    f32x4 acc[4][4] = {};
#pragma unroll
    for (int ks = 0; ks < 8; ks++) {
        size_t k0 = kbase + ks * 32;
        bf16x8 af[4], bh[4], bl[4];
#pragma unroll
        for (int mi = 0; mi < 4; mi++)
            af[mi] = *reinterpret_cast<const bf16x8*>(&h1t[(size_t)(m0 + mi * 16 + l15) * NP + k0]);
#pragma unroll
        for (int ni = 0; ni < 4; ni++) {
            bh[ni] = *reinterpret_cast<const bf16x8*>(&wthi[(size_t)(ni * 16 + l15) * NP + k0]);
            bl[ni] = *reinterpret_cast<const bf16x8*>(&wtlo[(size_t)(ni * 16 + l15) * NP + k0]);
        }
#pragma unroll
        for (int mi = 0; mi < 4; mi++)
#pragma unroll
            for (int ni = 0; ni < 4; ni++) {
                acc[mi][ni] = __builtin_amdgcn_mfma_f32_16x16x32_bf16(af[mi], bh[ni], acc[mi][ni], 0, 0, 0);
                acc[mi][ni] = __builtin_amdgcn_mfma_f32_16x16x32_bf16(af[mi], bl[ni], acc[mi][ni], 0, 0, 0);
            }
    }
    float* qp = &qpart[(size_t)blockIdx.x * NG * FH];
#pragma unroll
    for (int mi = 0; mi < 4; mi++) {
        int row0 = m0 + mi * 16 + quad * 4;          // k-dim 0..255 (4 consecutive)
#pragma unroll
        for (int ni = 0; ni < 4; ni++) {
            int col = ni * 16 + l15;                 // g-dim 0..63
            f32x4 o = {acc[mi][ni][0], acc[mi][ni][1], acc[mi][ni][2], acc[mi][ni][3]};
            *reinterpret_cast<f32x4*>(&qp[(size_t)col * FH + row0]) = o;
        }
    }
}

// ---------------- fused head: q-reduce + pooled = (q@W2)/cnt + b2 ; out = pooled@Wfc + bfc ----------------

__global__ __launch_bounds__(256)
void p2fc_kernel(const float* __restrict__ qpart, const float* __restrict__ W2,
                 const float* __restrict__ b2, const int* __restrict__ batch,
                 const float* __restrict__ Wfc, const float* __restrict__ bfc,
                 float* __restrict__ out) {
    __shared__ float qg[FH];
    __shared__ float ps[FH];
    int g = blockIdx.x;
    int t = threadIdx.x;
    float s = 0.0f;
    for (int b = 0; b < QSK; b++)                    // coalesced: consecutive t -> consecutive k
        s += qpart[(size_t)b * NG * FH + (size_t)g * FH + t];
    qg[t] = s;
    int lo = 0, hi = NNODES;
    while (lo < hi) { int m = (lo + hi) >> 1; if (batch[m] < g) lo = m + 1; else hi = m; }
    int a = lo;
    lo = 0; hi = NNODES;
    while (lo < hi) { int m = (lo + hi) >> 1; if (batch[m] < g + 1) lo = m + 1; else hi = m; }
    float inv = 1.0f / fmaxf((float)(lo - a), 1.0f);
    __syncthreads();
    float acc = 0.0f;
    for (int k = 0; k < FH; k++)
        acc += qg[k] * W2[k * FH + t];
    ps[t] = acc * inv + b2[t];
    __syncthreads();
    if (t < NC) {
        float a2 = 0.0f;
        for (int cc = 0; cc < FH; cc++)
            a2 += ps[cc] * Wfc[cc * NC + t];
        out[g * NC + t] = a2 + bfc[t];
    }
}

// ---------------- launch ----------------

extern "C" void kernel_launch(void* const* d_in, const int* in_sizes, int n_in,
                              void* d_out, int out_size, void* d_ws, size_t ws_size,
                              hipStream_t stream) {
    const float* x    = (const float*)d_in[0];
    const int*   ei   = (const int*)d_in[1];
    const int*   batch= (const int*)d_in[2];
    const float* W1   = (const float*)d_in[3];
    const float* b1   = (const float*)d_in[4];
    const float* W2   = (const float*)d_in[5];
    const float* b2   = (const float*)d_in[6];
    const float* Wfc  = (const float*)d_in[7];
    const float* bfc  = (const float*)d_in[8];
    float* out = (float*)d_out;

    const int* src = ei;
    const int* dst = ei + NEDGES;

    // workspace (~92 MB):
    bhalf* xb        = (bhalf*)d_ws;                       // [N,128] bf16 (12.8 MB)
    bhalf* zb        = xb + (size_t)NNODES * FIN;          // [N,128] bf16 (12.8 MB)
    bhalf* h1t       = zb + (size_t)NNODES * FIN;          // [256,NP] bf16 (25.7 MB)
    uint2* edata     = (uint2*)(h1t + (size_t)FH * NP);    // [E] {src, f32 norm} (6.4 MB)
    uint2* binned    = edata + NEDGES;                     // [NBUCK*BCAP] (8.0 MB)
    int*   row_start = (int*)(binned + (size_t)NBUCK * BCAP);  // [N]
    int*   local_ex  = row_start + NNODES;                 // [N]
    int*   partial   = local_ex + NNODES;                  // [256]
    int*   bcur      = partial + 256;                      // [256]
    float* dinv      = (float*)(bcur + 256);               // [N]
    bhalf* w1t       = (bhalf*)(dinv + NNODES);            // [256,128] bf16
    bhalf* wthi      = w1t + 256 * FIN;                    // [64,NP] bf16 (6.4 MB)
    bhalf* wtlo      = wthi + (size_t)NG * NP;             // [64,NP] bf16 (6.4 MB)
    float* qpart     = (float*)(wtlo + (size_t)NG * NP);   // [QSK,64,256] f32, [g][k] (12.85 MB)
    int*   degi      = (int*)(qpart + (size_t)QSK * NG * FH);  // [N] (memset)

    (void)hipMemsetAsync(degi, 0, (size_t)NNODES * 4, stream);

    // ---- CSR build + norms ----
    degree_splitx_kernel<<<DEG_BLOCKS + SPLITX_BLOCKS, 256, 0, stream>>>(dst, degi, x, xb);
    scan_block_kernel<<<SCAN_NB, 256, 0, stream>>>(degi, local_ex, partial, dinv, NNODES);
    add_offsets_kernel<<<SCAN_NB, 256, 0, stream>>>(row_start, local_ex, partial, bcur,
                                                    W1, w1t, NNODES);
    bin_kernel<<<BIN_BLOCKS, 256, 0, stream>>>(src, dst, dinv, bcur, binned);
    place_kernel<<<NBUCK, 256, 0, stream>>>(binned, bcur, row_start, edata);

    // conv1 (aggregate-first): z = bf16(Ahat*x) ; h1t = bf16(gelu(z@W1 + b1))^T
    gather128_kernel<<<(NNODES + 3) / 4, 256, 0, stream>>>(xb, edata, row_start, degi,
                                                           dinv, zb, NNODES);
    // pooling-weight matrix straight to bf16 hi/lo from CSR (no global atomics)
    wt_build_kernel<<<NG * 4, 256, 0, stream>>>(edata, row_start, batch, dinv, wthi, wtlo);
    gemm_kernel<<<GEMM_BLKS, 256, 0, stream>>>(zb, w1t, b1, h1t, NNODES, FIN);

    // conv2 + pool collapsed via MFMA: qT = h1t @ wt^T ; out = ((q@W2)/cnt + b2)@Wfc + bfc
    qsum_mfma_kernel<<<QSK, 256, 0, stream>>>(h1t, wthi, wtlo, qpart);
    p2fc_kernel<<<NG, FH, 0, stream>>>(qpart, W2, b2, batch, Wfc, bfc, out);
}

// Round 4
// 246.791 us; speedup vs baseline: 1.2244x; 1.1932x over previous
//
#include <hip/hip_runtime.h>
#include <hip/hip_bf16.h>
#include <hip/hip_fp16.h>
#include <math.h>

#define NNODES 50000
#define NEDGES 800000
#define FIN 128
#define FH 256
#define NG 64
#define NC 64
#define NP 50176              // K padded to 196*256
#define QSK 196               // split-K blocks for qsum (NP/256)
#define SPLITX_ITEMS (NNODES * FIN / 4)      // 1.6M
#define SPLITX_BLOCKS ((SPLITX_ITEMS + 255) / 256)   // 6250
#define W1T_BLOCKS (FIN * 256 / 256)         // 128
#define GEMM_MB ((NNODES + 127) / 128)       // 391
#define GEMM_BLKS (GEMM_MB * 2)              // 782
#define QTR (NP / 4)                         // 12544 src slots per wt-build block

#define NBUCK 196             // dst>>8 buckets (256 nodes each)
#define BCAP 5120             // per-bucket capacity (mean 4096, sigma ~64 -> +16 sigma)
#define BIN_CHUNK 2048        // edges per bin block
#define BIN_BLOCKS ((NEDGES + BIN_CHUNK - 1) / BIN_CHUNK)   // 391

typedef unsigned short bhalf;
typedef __attribute__((ext_vector_type(8))) short bf16x8;
typedef __attribute__((ext_vector_type(4))) float f32x4;
typedef __attribute__((ext_vector_type(4))) unsigned short u16x4;

__device__ inline bhalf f2bf_rn(float f) {
    unsigned int u = __float_as_uint(f);
    u += 0x7FFFu + ((u >> 16) & 1u);      // round-to-nearest-even
    return (bhalf)(u >> 16);
}
__device__ inline float bf2f(bhalf h) { return __uint_as_float(((unsigned int)h) << 16); }
__device__ inline float2 bfpair(unsigned int u) {   // [lo16, hi16] -> two floats
    return make_float2(__uint_as_float(u << 16), __uint_as_float(u & 0xFFFF0000u));
}

// ---------------- x->bf16 + W1 transpose + bcur init (block ranges; NO atomics) ----------------
// Degree counting via global atomics is eliminated: degrees fall out of the
// bucket histogram in place_kernel.

__global__ void splitx_kernel(const float* __restrict__ x, bhalf* __restrict__ xb,
                              const float* __restrict__ W1, bhalf* __restrict__ w1t,
                              int* __restrict__ bcur) {
    int b = blockIdx.x;
    if (b < SPLITX_BLOCKS) {
        int i = b * 256 + threadIdx.x;
        if (i < SPLITX_ITEMS) {
            float4 v = *reinterpret_cast<const float4*>(&x[i * 4]);
            u16x4 o = {f2bf_rn(v.x), f2bf_rn(v.y), f2bf_rn(v.z), f2bf_rn(v.w)};
            *reinterpret_cast<u16x4*>(&xb[i * 4]) = o;
        }
    } else if (b < SPLITX_BLOCKS + W1T_BLOCKS) {
        int i = (b - SPLITX_BLOCKS) * 256 + threadIdx.x;   // W1[K][256] -> w1t[256][K]
        int k = i >> 8, n = i & 255;
        w1t[n * FIN + k] = f2bf_rn(W1[i]);
    } else {
        if (threadIdx.x < NBUCK) bcur[threadIdx.x] = threadIdx.x * BCAP;
    }
}

// ---------------- pass 1: bucket binning with LDS staging, coalesced flushes ----------------
// 4B entries {dlo:8 | src:16}. One global atomic per (block,bucket) to reserve
// space; staged bucket-major so flushes are coalesced. No norm computed here
// (no dinv dependency).

__global__ __launch_bounds__(256)
void bin_kernel(const int* __restrict__ src, const int* __restrict__ dst,
                int* __restrict__ bcur, unsigned int* __restrict__ binned) {
    __shared__ int hist[NBUCK];
    __shared__ int base[NBUCK];
    __shared__ int gb[NBUCK];
    __shared__ int lcur[NBUCK];
    __shared__ int scan_tmp[256];
    __shared__ unsigned int stage[BIN_CHUNK];
    __shared__ unsigned char bid[BIN_CHUNK];
    int t = threadIdx.x;
    int e0 = blockIdx.x * BIN_CHUNK;
    for (int i = t; i < NBUCK; i += 256) hist[i] = 0;
    __syncthreads();
#pragma unroll
    for (int k = 0; k < BIN_CHUNK / 256; k++) {
        int e = e0 + k * 256 + t;
        if (e < NEDGES) atomicAdd(&hist[dst[e] >> 8], 1);
    }
    __syncthreads();
    // inclusive Hillis-Steele scan over 256 (NBUCK padded with zeros)
    int v = (t < NBUCK) ? hist[t] : 0;
    scan_tmp[t] = v;
    __syncthreads();
#pragma unroll
    for (int off = 1; off < 256; off <<= 1) {
        int x = (t >= off) ? scan_tmp[t - off] : 0;
        __syncthreads();
        scan_tmp[t] += x;
        __syncthreads();
    }
    if (t < NBUCK) {
        int ex = scan_tmp[t] - v;                // exclusive
        base[t] = ex;
        lcur[t] = ex;
        gb[t] = (v > 0) ? atomicAdd(&bcur[t], v) : 0;
    }
    __syncthreads();
#pragma unroll
    for (int k = 0; k < BIN_CHUNK / 256; k++) {
        int e = e0 + k * 256 + t;
        if (e < NEDGES) {
            int s = src[e], d = dst[e];
            int b = d >> 8;
            int lp = atomicAdd(&lcur[b], 1);
            stage[lp] = (unsigned int)s | ((unsigned int)(d & 255) << 16);
            bid[lp] = (unsigned char)b;          // b < 196 fits u8
        }
    }
    __syncthreads();
    int total = base[NBUCK - 1] + hist[NBUCK - 1];
    for (int i = t; i < total; i += 256) {
        int b = bid[i];
        binned[(size_t)gb[b] + (i - base[b])] = stage[i];
    }
}

// ---------------- pass 2: per-bucket degree+dinv+row_start+CSR placement ----------------
// All edges of a node are in its bucket => LDS histogram gives exact degrees,
// replacing 800K global degree atomics AND both scan kernels. Random writes
// stay inside the bucket's ~16KB CSR span (one XCD L2 -> full-line writeback).

__global__ __launch_bounds__(256)
void place_kernel(const unsigned int* __restrict__ binned, const int* __restrict__ bcur,
                  int* __restrict__ row_start, float* __restrict__ dinv,
                  unsigned int* __restrict__ edata) {
    __shared__ unsigned int stage[BCAP];
    __shared__ int sc[256];
    __shared__ int deg[256];
    __shared__ int lex[256];
    __shared__ int lcur[256];
    __shared__ unsigned short dih[256];
    __shared__ int s_ebase, s_cnt;
    int b = blockIdx.x, t = threadIdx.x;
    // exclusive prefix over bucket counts -> global edge base of this bucket
    int c = (t < NBUCK) ? (bcur[t] - t * BCAP) : 0;
    sc[t] = c;
    __syncthreads();
#pragma unroll
    for (int off = 1; off < 256; off <<= 1) {
        int x = (t >= off) ? sc[t - off] : 0;
        __syncthreads();
        sc[t] += x;
        __syncthreads();
    }
    if (t == b) { s_ebase = sc[t] - c; s_cnt = c; }
    deg[t] = 0;
    __syncthreads();
    int cnt = s_cnt, eb = s_ebase;
    const unsigned int* bp = &binned[(size_t)b * BCAP];
    for (int i = t; i < cnt; i += 256) stage[i] = bp[i];
    __syncthreads();
    for (int i = t; i < cnt; i += 256) atomicAdd(&deg[(stage[i] >> 16) & 255], 1);
    __syncthreads();
    int d = deg[t];
    float di = rsqrtf((float)d + 1.0f);
    int gn = (b << 8) + t;
    if (gn < NNODES) dinv[gn] = di;
    dih[t] = __half_as_ushort(__float2half(di));
    sc[t] = d;
    __syncthreads();
#pragma unroll
    for (int off = 1; off < 256; off <<= 1) {
        int x = (t >= off) ? sc[t - off] : 0;
        __syncthreads();
        sc[t] += x;
        __syncthreads();
    }
    int lexv = sc[t] - d;                        // exclusive within bucket
    lex[t] = lexv;
    lcur[t] = 0;
    if (gn <= NNODES) row_start[gn] = eb + lexv; // row_start[N] = E lands here too
    __syncthreads();
    for (int i = t; i < cnt; i += 256) {
        unsigned int e = stage[i];
        int dl = (e >> 16) & 255;
        int pos = eb + lex[dl] + atomicAdd(&lcur[dl], 1);
        edata[pos] = (e & 0xFFFFu) | ((unsigned int)dih[dl] << 16);
    }
}

// ---------------- CSR gather, 128 bf16 feats, factored norms ----------------
// z[d] = dinv[d] * (sum_s dinv[s]*x[s] + dinv[d]*x[d]); dinv[s] is a
// wave-uniform cached load (200KB table).

__global__ __launch_bounds__(256)
void gather128_kernel(const bhalf* __restrict__ xb, const unsigned int* __restrict__ edata,
                      const int* __restrict__ row_start, const float* __restrict__ dinv,
                      bhalf* __restrict__ z, int Nn) {
    int node = blockIdx.x * 4 + (threadIdx.x >> 6);
    if (node >= Nn) return;
    int lane = threadIdx.x & 63;
    int st = row_start[node];
    int cnt = row_start[node + 1] - st;
    float ax = 0.0f, ay = 0.0f;
    int j = 0;
    for (; j + 3 < cnt; j += 4) {
        unsigned int e0 = edata[st + j],     e1 = edata[st + j + 1];
        unsigned int e2 = edata[st + j + 2], e3 = edata[st + j + 3];
        int s0 = e0 & 0xFFFFu, s1 = e1 & 0xFFFFu, s2 = e2 & 0xFFFFu, s3 = e3 & 0xFFFFu;
        float2 v0 = bfpair(*reinterpret_cast<const unsigned int*>(&xb[(size_t)s0 * FIN + lane * 2]));
        float2 v1 = bfpair(*reinterpret_cast<const unsigned int*>(&xb[(size_t)s1 * FIN + lane * 2]));
        float2 v2 = bfpair(*reinterpret_cast<const unsigned int*>(&xb[(size_t)s2 * FIN + lane * 2]));
        float2 v3 = bfpair(*reinterpret_cast<const unsigned int*>(&xb[(size_t)s3 * FIN + lane * 2]));
        float n0 = dinv[s0], n1 = dinv[s1], n2 = dinv[s2], n3 = dinv[s3];
        ax += v0.x * n0 + v1.x * n1 + v2.x * n2 + v3.x * n3;
        ay += v0.y * n0 + v1.y * n1 + v2.y * n2 + v3.y * n3;
    }
    for (; j < cnt; j++) {
        unsigned int e0 = edata[st + j];
        int s0 = e0 & 0xFFFFu;
        float2 v0 = bfpair(*reinterpret_cast<const unsigned int*>(&xb[(size_t)s0 * FIN + lane * 2]));
        float n0 = dinv[s0];
        ax += v0.x * n0; ay += v0.y * n0;
    }
    float dn = dinv[node];
    float2 xv = bfpair(*reinterpret_cast<const unsigned int*>(&xb[(size_t)node * FIN + lane * 2]));
    ushort2 o = {f2bf_rn(dn * (ax + xv.x * dn)), f2bf_rn(dn * (ay + xv.y * dn))};
    *reinterpret_cast<ushort2*>(&z[(size_t)node * FIN + lane * 2]) = o;
}

// ---------------- wt build from CSR: one block per (graph, src-quarter) ----------------
// acc[s] accumulates f16(dinv[d]) over graph-g edges; epilogue multiplies by
// dinv[s] and adds the self-loop: wt[g][s] = dinv[s]*(acc + [s in g]*dinv[s]).

__global__ __launch_bounds__(256)
void wt_build_kernel(const unsigned int* __restrict__ edata, const int* __restrict__ row_start,
                     const int* __restrict__ batch, const float* __restrict__ dinv,
                     bhalf* __restrict__ wthi, bhalf* __restrict__ wtlo) {
    __shared__ float acc[QTR];
    int g = blockIdx.x >> 2;
    int q = blockIdx.x & 3;
    int base = q * QTR;
    for (int i = threadIdx.x; i < QTR; i += 256) acc[i] = 0.0f;
    // node range [na, nb) of graph g (batch sorted)
    int lo = 0, hi = NNODES;
    while (lo < hi) { int m = (lo + hi) >> 1; if (batch[m] < g) lo = m + 1; else hi = m; }
    int na = lo;
    hi = NNODES;               // nb >= na since sorted
    while (lo < hi) { int m = (lo + hi) >> 1; if (batch[m] < g + 1) lo = m + 1; else hi = m; }
    int nb = lo;
    int pa = row_start[na];
    int pb = row_start[nb];
    __syncthreads();
    for (int p = pa + threadIdx.x; p < pb; p += 256) {
        unsigned int e = edata[p];
        int s = (int)(e & 0xFFFFu) - base;
        if ((unsigned int)s < (unsigned int)QTR)
            atomicAdd(&acc[s], __half2float(__ushort_as_half((unsigned short)(e >> 16))));
    }
    __syncthreads();
    size_t rowo = (size_t)g * NP + base;
    for (int i = threadIdx.x; i < QTR; i += 256) {
        int s = base + i;
        float dv = (s < NNODES) ? dinv[s] : 0.0f;
        float v = acc[i];
        if (s >= na && s < nb) v += dv;          // self-loop (becomes dinv^2)
        v *= dv;
        bhalf hb = f2bf_rn(v);
        wthi[rowo + i] = hb;
        wtlo[rowo + i] = f2bf_rn(v - bf2f(hb));
    }
}

// ---------------- MFMA bf16 GEMM (transposed out): h1t = bf16(gelu(zb@w1t^T + b1))^T ----------------

__global__ __launch_bounds__(256)
void gemm_kernel(const bhalf* __restrict__ A, const bhalf* __restrict__ Bt,
                 const float* __restrict__ bias, bhalf* __restrict__ h1t, int M, int Kp) {
    __shared__ bhalf As[128 * 72];   // rows x (64+8 pad): 144 B row stride
    __shared__ bhalf Bs[128 * 72];
    const int tid  = threadIdx.x;
    const int lane = tid & 63;
    const int wave = tid >> 6;
    const int quad = lane >> 4;
    const int l15  = lane & 15;
    const int wm = (wave & 1) * 64;
    const int wn = (wave >> 1) * 64;
    const int bm = (blockIdx.x >> 1) * 128;
    const int bn = (blockIdx.x & 1) * 128;

    f32x4 acc[4][4] = {};

    for (int k0 = 0; k0 < Kp; k0 += 64) {
#pragma unroll
        for (int i = 0; i < 4; i++) {
            int chunk = tid + i * 256;           // 1024 chunks of 8 bf16
            int r = chunk >> 3, c16 = chunk & 7;
            int gm = bm + r;
            float4 va = make_float4(0.f, 0.f, 0.f, 0.f);
            if (gm < M) va = *reinterpret_cast<const float4*>(&A[(size_t)gm * Kp + k0 + c16 * 8]);
            *reinterpret_cast<float4*>(&As[r * 72 + c16 * 8]) = va;
            float4 vb = *reinterpret_cast<const float4*>(&Bt[(size_t)(bn + r) * Kp + k0 + c16 * 8]);
            *reinterpret_cast<float4*>(&Bs[r * 72 + c16 * 8]) = vb;
        }
        __syncthreads();
#pragma unroll
        for (int kk = 0; kk < 64; kk += 32) {
            bf16x8 af[4], bfr[4];
#pragma unroll
            for (int mi = 0; mi < 4; mi++)
                af[mi] = *reinterpret_cast<const bf16x8*>(&As[(wm + mi * 16 + l15) * 72 + kk + quad * 8]);
#pragma unroll
            for (int ni = 0; ni < 4; ni++)
                bfr[ni] = *reinterpret_cast<const bf16x8*>(&Bs[(wn + ni * 16 + l15) * 72 + kk + quad * 8]);
#pragma unroll
            for (int mi = 0; mi < 4; mi++)
#pragma unroll
                for (int ni = 0; ni < 4; ni++)
                    acc[mi][ni] = __builtin_amdgcn_mfma_f32_16x16x32_bf16(af[mi], bfr[ni], acc[mi][ni], 0, 0, 0);
        }
        __syncthreads();
    }

    // epilogue: C/D col = lane&15, row = quad*4 + r. Write transposed: h1t[col][row0..row0+3].
#pragma unroll
    for (int mi = 0; mi < 4; mi++) {
        int row0 = bm + wm + mi * 16 + quad * 4;
#pragma unroll
        for (int ni = 0; ni < 4; ni++) {
            int col = bn + wn + ni * 16 + l15;
            float bv = bias[col];
            u16x4 o;
#pragma unroll
            for (int r = 0; r < 4; r++) {
                float v = acc[mi][ni][r] + bv;
                v = 0.5f * v * (1.0f + erff(v * 0.70710678118654752f));
                o[r] = f2bf_rn(v);
            }
            *reinterpret_cast<u16x4*>(&h1t[(size_t)col * NP + row0]) = o;
        }
    }
}

// ---------------- qsum MFMA: qpart[b][g][k] = h1t @ {wthi,wtlo}^T over K chunk ----------------

__global__ __launch_bounds__(256)
void qsum_mfma_kernel(const bhalf* __restrict__ h1t, const bhalf* __restrict__ wthi,
                      const bhalf* __restrict__ wtlo, float* __restrict__ qpart) {
    const int tid  = threadIdx.x;
    const int lane = tid & 63;
    const int wave = tid >> 6;
    const int quad = lane >> 4;
    const int l15  = lane & 15;
    const int m0 = wave * 64;
    const size_t kbase = (size_t)blockIdx.x * 256 + quad * 8;
    f32x4 acc[4][4] = {};
#pragma unroll
    for (int ks = 0; ks < 8; ks++) {
        size_t k0 = kbase + ks * 32;
        bf16x8 af[4], bh[4], bl[4];
#pragma unroll
        for (int mi = 0; mi < 4; mi++)
            af[mi] = *reinterpret_cast<const bf16x8*>(&h1t[(size_t)(m0 + mi * 16 + l15) * NP + k0]);
#pragma unroll
        for (int ni = 0; ni < 4; ni++) {
            bh[ni] = *reinterpret_cast<const bf16x8*>(&wthi[(size_t)(ni * 16 + l15) * NP + k0]);
            bl[ni] = *reinterpret_cast<const bf16x8*>(&wtlo[(size_t)(ni * 16 + l15) * NP + k0]);
        }
#pragma unroll
        for (int mi = 0; mi < 4; mi++)
#pragma unroll
            for (int ni = 0; ni < 4; ni++) {
                acc[mi][ni] = __builtin_amdgcn_mfma_f32_16x16x32_bf16(af[mi], bh[ni], acc[mi][ni], 0, 0, 0);
                acc[mi][ni] = __builtin_amdgcn_mfma_f32_16x16x32_bf16(af[mi], bl[ni], acc[mi][ni], 0, 0, 0);
            }
    }
    float* qp = &qpart[(size_t)blockIdx.x * NG * FH];
#pragma unroll
    for (int mi = 0; mi < 4; mi++) {
        int row0 = m0 + mi * 16 + quad * 4;          // k-dim 0..255 (4 consecutive)
#pragma unroll
        for (int ni = 0; ni < 4; ni++) {
            int col = ni * 16 + l15;                 // g-dim 0..63
            f32x4 o = {acc[mi][ni][0], acc[mi][ni][1], acc[mi][ni][2], acc[mi][ni][3]};
            *reinterpret_cast<f32x4*>(&qp[(size_t)col * FH + row0]) = o;
        }
    }
}

// ---------------- fused head: q-reduce + pooled = (q@W2)/cnt + b2 ; out = pooled@Wfc + bfc ----------------

__global__ __launch_bounds__(256)
void p2fc_kernel(const float* __restrict__ qpart, const float* __restrict__ W2,
                 const float* __restrict__ b2, const int* __restrict__ batch,
                 const float* __restrict__ Wfc, const float* __restrict__ bfc,
                 float* __restrict__ out) {
    __shared__ float qg[FH];
    __shared__ float ps[FH];
    int g = blockIdx.x;
    int t = threadIdx.x;
    float s = 0.0f;
    for (int b = 0; b < QSK; b++)                    // coalesced: consecutive t -> consecutive k
        s += qpart[(size_t)b * NG * FH + (size_t)g * FH + t];
    qg[t] = s;
    int lo = 0, hi = NNODES;
    while (lo < hi) { int m = (lo + hi) >> 1; if (batch[m] < g) lo = m + 1; else hi = m; }
    int a = lo;
    lo = 0; hi = NNODES;
    while (lo < hi) { int m = (lo + hi) >> 1; if (batch[m] < g + 1) lo = m + 1; else hi = m; }
    float inv = 1.0f / fmaxf((float)(lo - a), 1.0f);
    __syncthreads();
    float acc = 0.0f;
    for (int k = 0; k < FH; k++)
        acc += qg[k] * W2[k * FH + t];
    ps[t] = acc * inv + b2[t];
    __syncthreads();
    if (t < NC) {
        float a2 = 0.0f;
        for (int cc = 0; cc < FH; cc++)
            a2 += ps[cc] * Wfc[cc * NC + t];
        out[g * NC + t] = a2 + bfc[t];
    }
}

// ---------------- launch ----------------

extern "C" void kernel_launch(void* const* d_in, const int* in_sizes, int n_in,
                              void* d_out, int out_size, void* d_ws, size_t ws_size,
                              hipStream_t stream) {
    const float* x    = (const float*)d_in[0];
    const int*   ei   = (const int*)d_in[1];
    const int*   batch= (const int*)d_in[2];
    const float* W1   = (const float*)d_in[3];
    const float* b1   = (const float*)d_in[4];
    const float* W2   = (const float*)d_in[5];
    const float* b2   = (const float*)d_in[6];
    const float* Wfc  = (const float*)d_in[7];
    const float* bfc  = (const float*)d_in[8];
    float* out = (float*)d_out;

    const int* src = ei;
    const int* dst = ei + NEDGES;

    // workspace (~85 MB):
    bhalf* xb        = (bhalf*)d_ws;                       // [N,128] bf16 (12.8 MB)
    bhalf* zb        = xb + (size_t)NNODES * FIN;          // [N,128] bf16 (12.8 MB)
    bhalf* h1t       = zb + (size_t)NNODES * FIN;          // [256,NP] bf16 (25.7 MB)
    unsigned int* edata  = (unsigned int*)(h1t + (size_t)FH * NP);  // [E] {f16 dinv_d | src} (3.2 MB)
    unsigned int* binned = edata + NEDGES;                 // [NBUCK*BCAP] u32 (4.0 MB)
    int*   row_start = (int*)(binned + (size_t)NBUCK * BCAP);  // [N+256]
    int*   bcur      = row_start + NNODES + 256;           // [256]
    float* dinv      = (float*)(bcur + 256);               // [N+256]
    bhalf* w1t       = (bhalf*)(dinv + NNODES + 256);      // [256,128] bf16
    bhalf* wthi      = w1t + 256 * FIN;                    // [64,NP] bf16 (6.4 MB)
    bhalf* wtlo      = wthi + (size_t)NG * NP;             // [64,NP] bf16 (6.4 MB)
    float* qpart     = (float*)(wtlo + (size_t)NG * NP);   // [QSK,64,256] f32, [g][k] (12.85 MB)

    // ---- CSR build + norms (no global atomics on hot paths, no memset) ----
    splitx_kernel<<<SPLITX_BLOCKS + W1T_BLOCKS + 1, 256, 0, stream>>>(x, xb, W1, w1t, bcur);
    bin_kernel<<<BIN_BLOCKS, 256, 0, stream>>>(src, dst, bcur, binned);
    place_kernel<<<NBUCK, 256, 0, stream>>>(binned, bcur, row_start, dinv, edata);

    // conv1 (aggregate-first): z = bf16(Ahat*x) ; h1t = bf16(gelu(z@W1 + b1))^T
    gather128_kernel<<<(NNODES + 3) / 4, 256, 0, stream>>>(xb, edata, row_start, dinv,
                                                           zb, NNODES);
    // pooling-weight matrix straight to bf16 hi/lo from CSR
    wt_build_kernel<<<NG * 4, 256, 0, stream>>>(edata, row_start, batch, dinv, wthi, wtlo);
    gemm_kernel<<<GEMM_BLKS, 256, 0, stream>>>(zb, w1t, b1, h1t, NNODES, FIN);

    // conv2 + pool collapsed via MFMA: qT = h1t @ wt^T ; out = ((q@W2)/cnt + b2)@Wfc + bfc
    qsum_mfma_kernel<<<QSK, 256, 0, stream>>>(h1t, wthi, wtlo, qpart);
    p2fc_kernel<<<NG, FH, 0, stream>>>(qpart, W2, b2, batch, Wfc, bfc, out);
}